// Round 13
// baseline (305.391 us; speedup 1.0000x reference)
//
#include <hip/hip_runtime.h>
#include <stdint.h>
#include <math.h>

#define DEVI __device__ __forceinline__

typedef __attribute__((ext_vector_type(8))) short sv8;
typedef __attribute__((ext_vector_type(4))) short sv4;
typedef __attribute__((ext_vector_type(4))) float fv4;

typedef __attribute__((address_space(1))) void av1_t;
typedef __attribute__((address_space(3))) void av3_t;

constexpr int Bb = 2, Tt = 2048, Ee = 1024, Hh = 16, Dd = 64, FFd = 4096;
constexpr int NN = Bb * Tt;  // 4096 token rows
constexpr float EPSv = 1e-5f;

#define WAIT_VM(n) asm volatile("s_waitcnt vmcnt(" #n ")" ::: "memory")
#define LGKM0 asm volatile("s_waitcnt lgkmcnt(0)" ::: "memory")

DEVI float b2f(unsigned short s) {
  union { unsigned u; float f; } v; v.u = ((unsigned)s) << 16; return v.f;
}
DEVI unsigned short f2b(float f) {
  union { float f; unsigned u; } v; v.f = f;
  return (unsigned short)((v.u + 0x7FFFu + ((v.u >> 16) & 1u)) >> 16);
}
DEVI unsigned short f2b_rtz(float f) {  // truncation: 1 VALU op (softmax P only)
  union { float f; unsigned u; } v; v.f = f;
  return (unsigned short)(v.u >> 16);
}

// global -> LDS direct (16B per lane). LDS dest must be wave-uniform base + lane*16.
DEVI void load_lds16(const void* g, void* s) {
  __builtin_amdgcn_global_load_lds((av1_t*)(unsigned long long)g,
                                   (av3_t*)(unsigned)(unsigned long long)s,
                                   16, 0, 0);
}

// ---------------- fp32 -> bf16 convert (optional scale fold) ----------------
__global__ __launch_bounds__(256) void cvt_kernel(const float* __restrict__ in,
                                                  unsigned short* __restrict__ out, int n,
                                                  float scale) {
  int i = (blockIdx.x * 256 + threadIdx.x) * 4;
  if (i >= n) return;
  float4 v = *(const float4*)(in + i);
  sv4 o;
  o[0] = (short)f2b(v.x * scale); o[1] = (short)f2b(v.y * scale);
  o[2] = (short)f2b(v.z * scale); o[3] = (short)f2b(v.w * scale);
  *(sv4*)(out + i) = o;
}

// -------- W1 convert, block-16 interleave: a-row r -> 32*(r>>4)+(r&15);
//          gate-row (r-FFd) -> 32*((r-FFd)>>4)+16+(r&15). Even 16-col fragment = a,
//          odd = gate, SAME output cols -> lane-local GEGLU in the GEMM epilogue.
__global__ __launch_bounds__(256) void cvt_w1_kernel(const float* __restrict__ in,
                                                     unsigned short* __restrict__ out) {
  int i = (blockIdx.x * 256 + threadIdx.x) * 4;  // flat over 2*FFd*Ee
  const int r = i >> 10, c = i & 1023;
  const int rp = (r < FFd) ? ((r >> 4) * 32 + (r & 15))
                           : (((r - FFd) >> 4) * 32 + 16 + (r & 15));
  float4 v = *(const float4*)(in + i);
  sv4 o;
  o[0] = (short)f2b(v.x); o[1] = (short)f2b(v.y);
  o[2] = (short)f2b(v.z); o[3] = (short)f2b(v.w);
  *(sv4*)(out + (size_t)rp * Ee + c) = o;
}

// ---------------- V transpose: qkv V-slice [t][h*64+d] -> vT[b][h][d][t] ----------
__global__ __launch_bounds__(256) void vt_kernel(const unsigned short* __restrict__ qkv,
                                                 unsigned short* __restrict__ vT) {
  const int bh = blockIdx.y;               // b*16+h
  const int b = bh >> 4, h = bh & 15;
  const int tt = blockIdx.x * 64;          // token tile
  const int tid = threadIdx.x;
  __shared__ unsigned short tile[64][65];  // +1 pad
  const int tr = tid >> 2, tc4 = (tid & 3) * 16;
  const unsigned short* src = qkv + (size_t)(b * Tt + tt + tr) * (3 * Ee) + 2 * Ee + h * 64 + tc4;
  const sv8 a0 = *(const sv8*)src;
  const sv8 a1 = *(const sv8*)(src + 8);
#pragma unroll
  for (int j = 0; j < 8; ++j) { tile[tr][tc4 + j] = a0[j]; tile[tr][tc4 + 8 + j] = a1[j]; }
  __syncthreads();
  unsigned short* dst = vT + ((size_t)bh * 64 + tr) * Tt + tt + tc4;
  sv8 o0, o1;
#pragma unroll
  for (int j = 0; j < 8; ++j) { o0[j] = (short)tile[tc4 + j][tr]; o1[j] = (short)tile[tc4 + 8 + j][tr]; }
  *(sv8*)dst = o0;
  *(sv8*)(dst + 8) = o1;
}

// ---------------- LayerNorm (fp32 in, bf16 out), one block per row ----------------
__global__ __launch_bounds__(256) void ln_kernel(const float* __restrict__ x,
                                                 const float* __restrict__ g,
                                                 const float* __restrict__ b,
                                                 unsigned short* __restrict__ out) {
  const int row = blockIdx.x, tid = threadIdx.x;
  const float4 v = *(const float4*)(x + (size_t)row * Ee + tid * 4);
  float s = v.x + v.y + v.z + v.w;
  float ss = v.x * v.x + v.y * v.y + v.z * v.z + v.w * v.w;
#pragma unroll
  for (int off = 32; off; off >>= 1) { s += __shfl_down(s, off); ss += __shfl_down(ss, off); }
  __shared__ float red[16];
  const int w = tid >> 6, l = tid & 63;
  if (l == 0) { red[w] = s; red[8 + w] = ss; }
  __syncthreads();
  s = red[0] + red[1] + red[2] + red[3];
  ss = red[8] + red[9] + red[10] + red[11];
  const float mean = s * (1.f / Ee);
  const float rstd = rsqrtf(ss * (1.f / Ee) - mean * mean + EPSv);
  const float4 gv = *(const float4*)(g + tid * 4);
  const float4 bv = *(const float4*)(b + tid * 4);
  sv4 o;
  o[0] = (short)f2b((v.x - mean) * rstd * gv.x + bv.x);
  o[1] = (short)f2b((v.y - mean) * rstd * gv.y + bv.y);
  o[2] = (short)f2b((v.z - mean) * rstd * gv.z + bv.z);
  o[3] = (short)f2b((v.w - mean) * rstd * gv.w + bv.w);
  *(sv4*)(out + (size_t)row * Ee + tid * 4) = o;
}

// ---------------- bf16 GEMM (128xBN, 4 waves) — QKV / Wo / W2 ----------------
// Depth-2 pipeline (R11 structure). Chunk swizzle (T2).
template <int OUTF32, int HASBIAS, int BN, int GEGLU>
__global__ __launch_bounds__(256) void gemm_bt(const unsigned short* __restrict__ A,
                                               const unsigned short* __restrict__ Bw,
                                               void* __restrict__ Cout,
                                               const float* __restrict__ bias,
                                               const float* __restrict__ res,
                                               int M, int K) {
  constexpr int NI = BN / 32;  // per-wave n-frags (wave covers BN/2 cols)
  __shared__ unsigned short lA[3][128 * 32];
  __shared__ unsigned short lB[3][BN * 32];
  const int tid = threadIdx.x;
  const int l = tid & 63, w = tid >> 6;
  const int wr = w >> 1, wc = w & 1;
  const int rowbase = blockIdx.y * 128, colbase = blockIdx.x * BN;

  const fv4 zero4 = {0.f, 0.f, 0.f, 0.f};
  fv4 acc[4][NI];
#pragma unroll
  for (int i = 0; i < 4; ++i)
#pragma unroll
    for (int j = 0; j < NI; ++j) acc[i][j] = zero4;

  const int c0 = tid, c1 = tid + 256;
  const int sw0 = ((c0 & 3) ^ ((c0 >> 3) & 3)) * 8;
  const int sw1 = ((c1 & 3) ^ ((c1 >> 3) & 3)) * 8;
  const unsigned short* Ag0 = A + (size_t)(rowbase + (c0 >> 2)) * K + sw0;
  const unsigned short* Ag1 = A + (size_t)(rowbase + (c1 >> 2)) * K + sw1;
  const unsigned short* Bg0 = Bw + (size_t)(colbase + (c0 >> 2)) * K + sw0;
  const unsigned short* Bg1 = Bw + (size_t)(colbase + ((BN == 128 ? c1 : c0) >> 2)) * K +
                              (BN == 128 ? sw1 : sw0);

  const int nk = K >> 5;

  auto stage = [&](int buf) {
    load_lds16(Ag0, lA[buf] + c0 * 8);
    load_lds16(Ag1, lA[buf] + c1 * 8);
    load_lds16(Bg0, lB[buf] + c0 * 8);
    if (BN == 128) load_lds16(Bg1, lB[buf] + c1 * 8);
    Ag0 += 32; Ag1 += 32; Bg0 += 32; Bg1 += 32;
  };

  stage(0);
  stage(1);
  if constexpr (BN == 128) WAIT_VM(4); else WAIT_VM(3);
  __builtin_amdgcn_s_barrier();

  int cur = 0;
  for (int t = 0; t < nk; ++t) {
    const int pf = (cur + 2 >= 3) ? cur - 1 : cur + 2;  // (cur+2)%3
    if (t + 2 < nk) stage(pf);
    sv8 af[4], bfr[NI];
#pragma unroll
    for (int i = 0; i < 4; ++i) {
      const int ra = wr * 64 + i * 16 + (l & 15);
      af[i] = *(const sv8*)(lA[cur] + ra * 32 + (((l >> 4) ^ ((ra >> 1) & 3)) * 8));
    }
#pragma unroll
    for (int i = 0; i < NI; ++i) {
      const int rb = wc * (BN / 2) + i * 16 + (l & 15);
      bfr[i] = *(const sv8*)(lB[cur] + rb * 32 + (((l >> 4) ^ ((rb >> 1) & 3)) * 8));
    }
    __builtin_amdgcn_s_setprio(1);
#pragma unroll
    for (int mi = 0; mi < 4; ++mi)
#pragma unroll
      for (int ni = 0; ni < NI; ++ni)
        acc[mi][ni] = __builtin_amdgcn_mfma_f32_16x16x32_bf16(af[mi], bfr[ni], acc[mi][ni], 0, 0, 0);
    __builtin_amdgcn_s_setprio(0);
    if (t + 2 < nk) {
      if constexpr (BN == 128) WAIT_VM(4); else WAIT_VM(3);
      __builtin_amdgcn_s_barrier();
    } else if (t + 1 < nk) {
      WAIT_VM(0);
      __builtin_amdgcn_s_barrier();
    }
    cur = (cur + 1 >= 3) ? 0 : cur + 1;
  }

  const int r0 = rowbase + wr * 64 + ((l >> 4) * 4);
  const int ccol = colbase + wc * (BN / 2) + (l & 15);
#pragma unroll
  for (int mi = 0; mi < 4; ++mi) {
#pragma unroll
    for (int j = 0; j < 4; ++j) {
      const size_t r = (size_t)(r0 + mi * 16 + j);
      if (GEGLU) {
#pragma unroll
        for (int p = 0; p < NI / 2; ++p) {
          const int ca = ccol + p * 32;
          const int ocol = ((ca >> 5) << 4) | (ca & 15);
          const float av = acc[mi][2 * p][j] + bias[ocol];
          const float gv = acc[mi][2 * p + 1][j] + bias[ocol + (M >> 1)];
          const float y = 0.7978845608028654f * (gv + 0.044715f * gv * gv * gv);
          const float e = exp2f(2.8853900817779268f * y);
          const float gel = gv * (1.f - 1.f / (e + 1.f));
          ((unsigned short*)Cout)[r * (size_t)(M >> 1) + ocol] = f2b(av * gel);
        }
      } else {
#pragma unroll
        for (int ni = 0; ni < NI; ++ni) {
          const int c = ccol + ni * 16;
          float vv = acc[mi][ni][j];
          if (HASBIAS) vv += bias[c];
          if (OUTF32) {
            ((float*)Cout)[r * M + c] = res[r * M + c] + vv;
          } else {
            ((unsigned short*)Cout)[r * M + c] = f2b(vv);
          }
        }
      }
    }
  }
}

// ------- 256x256 8-wave GEMM, m201-skeleton 4-phase/K-tile schedule — W1 -------
// BK=64 = 2 K-half units of 256x32 per operand; unit = 2 global_load_lds/thread.
// Per phase: [ds_read frags][stage 1 unit of tile t+1 -> OPPOSITE dbuf parity]
//   [counted vmcnt at ph1/ph3 only][s_barrier][lgkmcnt(0)+sched_barrier]
//   [setprio(1) 16 MFMA setprio(0)][s_barrier].
// Gating proof: unit staged at (t-1,p) is first read at (t,p'); between them sits
// a vmcnt gate allowing only the 2 newest units (4 loads) outstanding + a barrier.
// ph1 gate covers k1(t) (read ph2/ph3); ph3 gate covers k0(t+1) (read next ph0/ph1).
// Loads thus stay in flight ACROSS barriers (T4); never drained mid-loop.
// Tail: t==nk-1 -> ph1 gate = vmcnt(0), ph3 gate skipped. Uniform control flow.
template <int GEGLU>
__global__ __launch_bounds__(512, 2) void gemm256(const unsigned short* __restrict__ A,
                                                  const unsigned short* __restrict__ Bw,
                                                  void* __restrict__ Cout,
                                                  const float* __restrict__ bias,
                                                  int M, int K) {
  __shared__ unsigned short Ah[2][2][256 * 32];  // [dbuf parity][khalf]
  __shared__ unsigned short Bh[2][2][256 * 32];
  const int tid = threadIdx.x;
  const int l = tid & 63, w = tid >> 6;
  const int wrow = w >> 2, wcol = w & 3;   // 2 x 4 wave grid
  const int nbase = blockIdx.y * 256, mbase = blockIdx.x * 256;

  const fv4 zero4 = {0.f, 0.f, 0.f, 0.f};
  fv4 acc[8][4];
#pragma unroll
  for (int i = 0; i < 8; ++i)
#pragma unroll
    for (int j = 0; j < 4; ++j) acc[i][j] = zero4;

  // staging: each unit = 1024 slots of 16B; thread handles slots tid and tid+512.
  const int s0 = tid, s1 = tid + 512;
  const int r0 = s0 >> 2, x0 = (((s0 & 3) ^ ((r0 >> 1) & 3))) * 8;
  const int r1 = s1 >> 2, x1 = (((s1 & 3) ^ ((r1 >> 1) & 3))) * 8;
  const unsigned short* As0 = A + (size_t)(nbase + r0) * K + x0;
  const unsigned short* As1 = A + (size_t)(nbase + r1) * K + x1;
  const unsigned short* Bs0 = Bw + (size_t)(mbase + r0) * K + x0;
  const unsigned short* Bs1 = Bw + (size_t)(mbase + r1) * K + x1;

  const int nk = K >> 6;

  auto stA = [&](int db, int kh, int kof) {
    load_lds16(As0 + kof + kh * 32, &Ah[db][kh][s0 * 8]);
    load_lds16(As1 + kof + kh * 32, &Ah[db][kh][s1 * 8]);
  };
  auto stB = [&](int db, int kh, int kof) {
    load_lds16(Bs0 + kof + kh * 32, &Bh[db][kh][s0 * 8]);
    load_lds16(Bs1 + kof + kh * 32, &Bh[db][kh][s1 * 8]);
  };

  // read-side swizzle: chunk' = (l>>4) ^ ((row>>1)&3); row = 16m+(l&15) -> (l>>1)&3
  const int cl = (((l >> 4) ^ ((l >> 1) & 3))) * 8;
  const int arl = (wrow * 128 + (l & 15)) * 32 + cl;
  const int brl = (wcol * 64 + (l & 15)) * 32 + cl;

  // prologue: tile 0's four units; allow k1 units to keep flying (vmcnt(4))
  stA(0, 0, 0); stB(0, 0, 0); stA(0, 1, 0); stB(0, 1, 0);
  WAIT_VM(4);
  __builtin_amdgcn_s_barrier();

  for (int t = 0; t < nk; ++t) {
    const int st = t & 1, sf = st ^ 1;
    const int kof = (t + 1) * 64;
    const bool pre = (t + 1 < nk);
    sv8 af[8], b0, b1;

    // ---- ph0: frags A.k0 + B.k0(ni01); stage A.k0(t+1) ----
#pragma unroll
    for (int mi = 0; mi < 8; ++mi) af[mi] = *(const sv8*)(&Ah[st][0][arl + mi * 512]);
    b0 = *(const sv8*)(&Bh[st][0][brl]);
    b1 = *(const sv8*)(&Bh[st][0][brl + 512]);
    if (pre) stA(sf, 0, kof);
    __builtin_amdgcn_s_barrier();
    LGKM0;
    __builtin_amdgcn_sched_barrier(0);
    __builtin_amdgcn_s_setprio(1);
#pragma unroll
    for (int mi = 0; mi < 8; ++mi) {
      acc[mi][0] = __builtin_amdgcn_mfma_f32_16x16x32_bf16(af[mi], b0, acc[mi][0], 0, 0, 0);
      acc[mi][1] = __builtin_amdgcn_mfma_f32_16x16x32_bf16(af[mi], b1, acc[mi][1], 0, 0, 0);
    }
    __builtin_amdgcn_s_setprio(0);
    __builtin_amdgcn_s_barrier();

    // ---- ph1: frags B.k0(ni23); stage B.k0(t+1); GATE k1(t) ----
    b0 = *(const sv8*)(&Bh[st][0][brl + 2 * 512]);
    b1 = *(const sv8*)(&Bh[st][0][brl + 3 * 512]);
    if (pre) { stB(sf, 0, kof); WAIT_VM(4); } else { WAIT_VM(0); }
    __builtin_amdgcn_s_barrier();
    LGKM0;
    __builtin_amdgcn_sched_barrier(0);
    __builtin_amdgcn_s_setprio(1);
#pragma unroll
    for (int mi = 0; mi < 8; ++mi) {
      acc[mi][2] = __builtin_amdgcn_mfma_f32_16x16x32_bf16(af[mi], b0, acc[mi][2], 0, 0, 0);
      acc[mi][3] = __builtin_amdgcn_mfma_f32_16x16x32_bf16(af[mi], b1, acc[mi][3], 0, 0, 0);
    }
    __builtin_amdgcn_s_setprio(0);
    __builtin_amdgcn_s_barrier();

    // ---- ph2: frags A.k1 + B.k1(ni01); stage A.k1(t+1) ----
#pragma unroll
    for (int mi = 0; mi < 8; ++mi) af[mi] = *(const sv8*)(&Ah[st][1][arl + mi * 512]);
    b0 = *(const sv8*)(&Bh[st][1][brl]);
    b1 = *(const sv8*)(&Bh[st][1][brl + 512]);
    if (pre) stA(sf, 1, kof);
    __builtin_amdgcn_s_barrier();
    LGKM0;
    __builtin_amdgcn_sched_barrier(0);
    __builtin_amdgcn_s_setprio(1);
#pragma unroll
    for (int mi = 0; mi < 8; ++mi) {
      acc[mi][0] = __builtin_amdgcn_mfma_f32_16x16x32_bf16(af[mi], b0, acc[mi][0], 0, 0, 0);
      acc[mi][1] = __builtin_amdgcn_mfma_f32_16x16x32_bf16(af[mi], b1, acc[mi][1], 0, 0, 0);
    }
    __builtin_amdgcn_s_setprio(0);
    __builtin_amdgcn_s_barrier();

    // ---- ph3: frags B.k1(ni23); stage B.k1(t+1); GATE k0(t+1) ----
    b0 = *(const sv8*)(&Bh[st][1][brl + 2 * 512]);
    b1 = *(const sv8*)(&Bh[st][1][brl + 3 * 512]);
    if (pre) { stB(sf, 1, kof); WAIT_VM(4); }
    __builtin_amdgcn_s_barrier();
    LGKM0;
    __builtin_amdgcn_sched_barrier(0);
    __builtin_amdgcn_s_setprio(1);
#pragma unroll
    for (int mi = 0; mi < 8; ++mi) {
      acc[mi][2] = __builtin_amdgcn_mfma_f32_16x16x32_bf16(af[mi], b0, acc[mi][2], 0, 0, 0);
      acc[mi][3] = __builtin_amdgcn_mfma_f32_16x16x32_bf16(af[mi], b1, acc[mi][3], 0, 0, 0);
    }
    __builtin_amdgcn_s_setprio(0);
    __builtin_amdgcn_s_barrier();
  }

  // ---- epilogue: C/D layout col=lane&15, row=(l>>4)*4+j ----
  const int rbase = nbase + wrow * 128 + ((l >> 4) * 4);
  const int cbase = mbase + wcol * 64 + (l & 15);
#pragma unroll
  for (int mi = 0; mi < 8; ++mi) {
#pragma unroll
    for (int j = 0; j < 4; ++j) {
      const size_t r = (size_t)(rbase + mi * 16 + j);
      if (GEGLU) {
#pragma unroll
        for (int p = 0; p < 2; ++p) {
          const int ca = cbase + p * 32;                   // even fragment (a); bit4 == 0
          const int ocol = ((ca >> 5) << 4) | (ca & 15);   // original column
          const float av = acc[mi][2 * p][j] + bias[ocol];
          const float gv = acc[mi][2 * p + 1][j] + bias[ocol + (M >> 1)];
          const float y = 0.7978845608028654f * (gv + 0.044715f * gv * gv * gv);
          const float e = exp2f(2.8853900817779268f * y);  // exp(2y)
          const float gel = gv * (1.f - 1.f / (e + 1.f));  // == 0.5*g*(1+tanh(y))
          ((unsigned short*)Cout)[r * (size_t)(M >> 1) + ocol] = f2b(av * gel);
        }
      } else {
#pragma unroll
        for (int ni = 0; ni < 4; ++ni) {
          const int c = cbase + ni * 16;
          ((unsigned short*)Cout)[r * (size_t)M + c] = f2b(acc[mi][ni][j]);
        }
      }
    }
  }
}

// ---------------- flash attention (unchanged) ----------------
__global__ __launch_bounds__(256) void attn_kernel(const unsigned short* __restrict__ Q,
                                                   const unsigned short* __restrict__ Kb,
                                                   const unsigned short* __restrict__ vT,
                                                   unsigned short* __restrict__ O,
                                                   int ld) {
  const int bidl = ((blockIdx.x & 7) << 7) + (blockIdx.x >> 3);  // 1024 = 8 XCD x 128
  const int bh = bidl >> 5;
  const int b = bh / Hh, h = bh % Hh;
  const int q0 = (bidl & 31) * 64;
  const int tid = threadIdx.x, l = tid & 63, w = tid >> 6;
  const size_t base = (size_t)b * Tt * ld + (size_t)h * Dd;
  const size_t baseO = (size_t)b * Tt * Ee + (size_t)h * Dd;
  const unsigned short* vTb = vT + (size_t)bh * 64 * Tt;  // [64 d][2048 t]

  __shared__ unsigned short Kt[2][64 * 64];
  __shared__ unsigned short Vt[2][64 * 64];
  __shared__ unsigned short Pt[4][16 * 64];

  sv8 qf0, qf1;
  {
    const unsigned short* qp = Q + base + (size_t)(q0 + w * 16 + (l & 15)) * ld + (l >> 4) * 8;
    qf0 = *(const sv8*)qp;
    qf1 = *(const sv8*)(qp + 32);
  }

  const fv4 zero4 = {0.f, 0.f, 0.f, 0.f};
  fv4 acc_o[4];
#pragma unroll
  for (int i = 0; i < 4; ++i) acc_o[i] = zero4;
  float Mx = -INFINITY;
  float Lp[4];
#pragma unroll
  for (int j = 0; j < 4; ++j) Lp[j] = 0.f;

  const int c0 = tid, c1 = tid + 256;
  const int r0c = c0 >> 3, xc0 = c0 & 7;
  const int r1c = c1 >> 3, xc1 = c1 & 7;

  load_lds16(Kb + base + (size_t)(r0c)*ld + (xc0 ^ (r0c & 7)) * 8, Kt[0] + c0 * 8);
  load_lds16(Kb + base + (size_t)(r1c)*ld + (xc1 ^ (r1c & 7)) * 8, Kt[0] + c1 * 8);
  load_lds16(vTb + (size_t)(r0c)*Tt + (xc0 ^ (r0c & 7)) * 8, Vt[0] + c0 * 8);
  load_lds16(vTb + (size_t)(r1c)*Tt + (xc1 ^ (r1c & 7)) * 8, Vt[0] + c1 * 8);
  __syncthreads();

  int cur = 0;
  for (int kt = 0; kt < Tt / 64; ++kt) {
    const int nx = cur ^ 1;
    if (kt + 1 < Tt / 64) {
      load_lds16(Kb + base + (size_t)((kt + 1) * 64 + r0c) * ld + (xc0 ^ (r0c & 7)) * 8, Kt[nx] + c0 * 8);
      load_lds16(Kb + base + (size_t)((kt + 1) * 64 + r1c) * ld + (xc1 ^ (r1c & 7)) * 8, Kt[nx] + c1 * 8);
      load_lds16(vTb + (size_t)(r0c)*Tt + (kt + 1) * 64 + (xc0 ^ (r0c & 7)) * 8, Vt[nx] + c0 * 8);
      load_lds16(vTb + (size_t)(r1c)*Tt + (kt + 1) * 64 + (xc1 ^ (r1c & 7)) * 8, Vt[nx] + c1 * 8);
    }

    fv4 s[4];
    __builtin_amdgcn_s_setprio(1);
#pragma unroll
    for (int ks = 0; ks < 4; ++ks) {
      const int row = ks * 16 + (l & 15);
      const sv8 kf0 = *(const sv8*)(Kt[cur] + row * 64 + (((l >> 4) ^ (row & 7)) * 8));
      const sv8 kf1 = *(const sv8*)(Kt[cur] + row * 64 + (((4 + (l >> 4)) ^ (row & 7)) * 8));
      fv4 t = zero4;
      t = __builtin_amdgcn_mfma_f32_16x16x32_bf16(qf0, kf0, t, 0, 0, 0);
      t = __builtin_amdgcn_mfma_f32_16x16x32_bf16(qf1, kf1, t, 0, 0, 0);
      s[ks] = t;
    }
    __builtin_amdgcn_s_setprio(0);

    float m01 = fmaxf(fmaxf(s[0][0], s[0][1]), fmaxf(s[0][2], s[0][3]));
    float m1 = fmaxf(fmaxf(s[1][0], s[1][1]), fmaxf(s[1][2], s[1][3]));
    float m2 = fmaxf(fmaxf(s[2][0], s[2][1]), fmaxf(s[2][2], s[2][3]));
    float m3 = fmaxf(fmaxf(s[3][0], s[3][1]), fmaxf(s[3][2], s[3][3]));
    float tm = fmaxf(fmaxf(m01, m1), fmaxf(m2, m3));
    if (__any(tm > Mx + 11.5f)) {
      float mt = tm;
#pragma unroll
      for (int off = 1; off < 16; off <<= 1) mt = fmaxf(mt, __shfl_xor(mt, off, 16));
      const float mnew = fmaxf(Mx, mt);
      const float alpha = exp2f(Mx - mnew);
      Mx = mnew;
#pragma unroll
      for (int j = 0; j < 4; ++j) {
        Lp[j] *= alpha;
#pragma unroll
        for (int dsb = 0; dsb < 4; ++dsb) acc_o[dsb][j] *= alpha;
      }
    }
#pragma unroll
    for (int ks = 0; ks < 4; ++ks)
#pragma unroll
      for (int j = 0; j < 4; ++j) {
        const float p = exp2f(s[ks][j] - Mx);
        s[ks][j] = p;
        Lp[j] += p;
      }
#pragma unroll
    for (int ks = 0; ks < 4; ++ks)
#pragma unroll
      for (int j = 0; j < 4; ++j) {
        const int q = (l >> 4) * 4 + j, k = ks * 16 + (l & 15);
        Pt[w][q * 64 + ((((k >> 3) ^ (q & 7)) & 7) * 8) + (k & 7)] = f2b_rtz(s[ks][j]);
      }
    LGKM0;

    __builtin_amdgcn_s_setprio(1);
#pragma unroll
    for (int kcn = 0; kcn < 2; ++kcn) {
      const int qr = l & 15;
      const sv8 pf = *(const sv8*)(&Pt[w][qr * 64 + (((kcn * 4 + (l >> 4)) ^ (qr & 7)) * 8)]);
#pragma unroll
      for (int dsb = 0; dsb < 4; ++dsb) {
        const int row = dsb * 16 + (l & 15);
        const int chunk = kcn * 4 + (l >> 4);
        const sv8 vf = *(const sv8*)(Vt[cur] + row * 64 + ((chunk ^ (row & 7)) * 8));
        acc_o[dsb] = __builtin_amdgcn_mfma_f32_16x16x32_bf16(pf, vf, acc_o[dsb], 0, 0, 0);
      }
    }
    __builtin_amdgcn_s_setprio(0);

    __syncthreads();
    cur = nx;
  }

#pragma unroll
  for (int j = 0; j < 4; ++j) {
    float t = Lp[j];
#pragma unroll
    for (int off = 1; off < 16; off <<= 1) t += __shfl_xor(t, off, 16);
    const float inv = 1.f / t;
    unsigned short* op = O + baseO + (size_t)(q0 + w * 16 + (l >> 4) * 4 + j) * Ee;
#pragma unroll
    for (int dsb = 0; dsb < 4; ++dsb)
      op[dsb * 16 + (l & 15)] = f2b(acc_o[dsb][j] * inv);
  }
}

extern "C" void kernel_launch(void* const* d_in, const int* in_sizes, int n_in,
                              void* d_out, int out_size, void* d_ws, size_t ws_size,
                              hipStream_t stream) {
  (void)in_sizes; (void)n_in; (void)out_size; (void)ws_size;
  const float* src  = (const float*)d_in[0];
  const float* Wq   = (const float*)d_in[1];
  const float* Wk   = (const float*)d_in[2];
  const float* Wv   = (const float*)d_in[3];
  const float* Wo   = (const float*)d_in[4];
  const float* W1   = (const float*)d_in[5];
  const float* b1   = (const float*)d_in[6];
  const float* W2   = (const float*)d_in[7];
  const float* b2   = (const float*)d_in[8];
  const float* ln1w = (const float*)d_in[9];
  const float* ln1b = (const float*)d_in[10];
  const float* ln2w = (const float*)d_in[11];
  const float* ln2b = (const float*)d_in[12];
  float* out = (float*)d_out;

  char* ws = (char*)d_ws;
  size_t off = 0;
  auto alloc = [&](size_t bytes) { char* p = ws + off; off += bytes; return p; };
  unsigned short* wqkv = (unsigned short*)alloc((size_t)3 * Ee * Ee * 2);  // Wq|Wk|Wv rows
  unsigned short* wo16 = (unsigned short*)alloc((size_t)Ee * Ee * 2);
  unsigned short* w116 = (unsigned short*)alloc((size_t)2 * FFd * Ee * 2); // interleaved
  unsigned short* w216 = (unsigned short*)alloc((size_t)Ee * FFd * 2);
  unsigned short* h16  = (unsigned short*)alloc((size_t)NN * Ee * 2);
  unsigned short* qkv  = (unsigned short*)alloc((size_t)NN * 3 * Ee * 2);  // [row][3E]
  unsigned short* a16  = (unsigned short*)alloc((size_t)NN * Ee * 2);
  float* xbuf          = (float*)alloc((size_t)NN * Ee * 4);
  unsigned short* vT   = (unsigned short*)alloc((size_t)NN * Ee * 2);      // [b][h][64][T]
  unsigned short* f16  = qkv;  // reuse qkv+a16 region (32 MB) after attention done

  const float s2 = 0.125f * 1.4426950408889634f;  // 1/sqrt(D) * log2(e), folded into Wq

  dim3 blk(256);
  cvt_kernel<<<dim3(Ee * Ee / 1024), blk, 0, stream>>>(Wq, wqkv, Ee * Ee, s2);
  cvt_kernel<<<dim3(Ee * Ee / 1024), blk, 0, stream>>>(Wk, wqkv + Ee * Ee, Ee * Ee, 1.0f);
  cvt_kernel<<<dim3(Ee * Ee / 1024), blk, 0, stream>>>(Wv, wqkv + 2 * Ee * Ee, Ee * Ee, 1.0f);
  cvt_kernel<<<dim3(Ee * Ee / 1024), blk, 0, stream>>>(Wo, wo16, Ee * Ee, 1.0f);
  cvt_w1_kernel<<<dim3(2 * FFd * Ee / 1024), blk, 0, stream>>>(W1, w116);
  cvt_kernel<<<dim3(Ee * FFd / 1024), blk, 0, stream>>>(W2, w216, Ee * FFd, 1.0f);

  ln_kernel<<<dim3(NN), blk, 0, stream>>>(src, ln1w, ln1b, h16);

  // fused QKV projection: [4096,1024] x [3072,1024]^T -> [4096,3072]
  gemm_bt<0, 0, 128, 0><<<dim3(3 * Ee / 128, NN / 128), blk, 0, stream>>>(h16, wqkv, qkv, nullptr, nullptr, 3 * Ee, Ee);

  // V transpose: [t][h*64+d] -> vT[b][h][d][t]
  vt_kernel<<<dim3(Tt / 64, Bb * Hh), blk, 0, stream>>>(qkv, vT);

  attn_kernel<<<dim3(1024), blk, 0, stream>>>(qkv, qkv + Ee, vT, a16, 3 * Ee);

  // Wo projection + residual (BN=64: 512 blocks, 2/CU)
  gemm_bt<1, 0, 64, 0><<<dim3(Ee / 64, NN / 128), blk, 0, stream>>>(a16, wo16, xbuf, nullptr, src, Ee, Ee);

  ln_kernel<<<dim3(NN), blk, 0, stream>>>(xbuf, ln2w, ln2b, h16);

  // W1 (block-16 interleaved) + lane-local GEGLU, 256x256 m201-skeleton kernel
  gemm256<1><<<dim3(2 * FFd / 256, NN / 256), dim3(512), 0, stream>>>(h16, w116, f16, b1, 2 * FFd, Ee);

  // W2 projection + bias + residual (BN=64: 512 blocks, 2/CU)
  gemm_bt<1, 1, 64, 0><<<dim3(Ee / 64, NN / 128), blk, 0, stream>>>(f16, w216, out, b2, xbuf, Ee, FFd);
}

// Round 14
// 292.532 us; speedup vs baseline: 1.0440x; 1.0440x over previous
//
#include <hip/hip_runtime.h>
#include <stdint.h>
#include <math.h>

#define DEVI __device__ __forceinline__

typedef __attribute__((ext_vector_type(8))) short sv8;
typedef __attribute__((ext_vector_type(4))) short sv4;
typedef __attribute__((ext_vector_type(4))) float fv4;

typedef __attribute__((address_space(1))) void av1_t;
typedef __attribute__((address_space(3))) void av3_t;

constexpr int Bb = 2, Tt = 2048, Ee = 1024, Hh = 16, Dd = 64, FFd = 4096;
constexpr int NN = Bb * Tt;  // 4096 token rows
constexpr float EPSv = 1e-5f;

#define WAIT_VM(n) asm volatile("s_waitcnt vmcnt(" #n ")" ::: "memory")
#define LGKM0 asm volatile("s_waitcnt lgkmcnt(0)" ::: "memory")

DEVI float b2f(unsigned short s) {
  union { unsigned u; float f; } v; v.u = ((unsigned)s) << 16; return v.f;
}
DEVI unsigned short f2b(float f) {
  union { float f; unsigned u; } v; v.f = f;
  return (unsigned short)((v.u + 0x7FFFu + ((v.u >> 16) & 1u)) >> 16);
}
DEVI unsigned short f2b_rtz(float f) {  // truncation: 1 VALU op (softmax P only)
  union { float f; unsigned u; } v; v.f = f;
  return (unsigned short)(v.u >> 16);
}

// global -> LDS direct (16B per lane). LDS dest must be wave-uniform base + lane*16.
DEVI void load_lds16(const void* g, void* s) {
  __builtin_amdgcn_global_load_lds((av1_t*)(unsigned long long)g,
                                   (av3_t*)(unsigned)(unsigned long long)s,
                                   16, 0, 0);
}

// ------------- merged weight convert: all 6 weights in ONE launch -------------
// bid [0,4096): square weights (Wq*s2, Wk, Wv -> wqkv; Wo -> wo16), 1024 blocks each
// bid [4096,12288): W1 with block-16 interleave (a-row r -> 32*(r>>4)+(r&15);
//                   gate-row -> +16) so even/odd 16-col fragments pair lane-locally.
// bid [12288,16384): W2.
__global__ __launch_bounds__(256) void cvt_all_kernel(
    const float* __restrict__ Wq, const float* __restrict__ Wk,
    const float* __restrict__ Wv, const float* __restrict__ Wo,
    const float* __restrict__ W1, const float* __restrict__ W2,
    unsigned short* __restrict__ wqkv, unsigned short* __restrict__ wo16,
    unsigned short* __restrict__ w116, unsigned short* __restrict__ w216,
    float s2) {
  const int bid = blockIdx.x;
  if (bid < 4096) {
    const int wsel = bid >> 10;  // 0:Wq 1:Wk 2:Wv 3:Wo
    const int i = ((bid & 1023) * 256 + threadIdx.x) * 4;
    const float* src = (wsel == 0) ? Wq : (wsel == 1) ? Wk : (wsel == 2) ? Wv : Wo;
    unsigned short* dst = (wsel == 3) ? wo16 : (wqkv + (size_t)wsel * Ee * Ee);
    const float sc = (wsel == 0) ? s2 : 1.0f;
    const float4 v = *(const float4*)(src + i);
    sv4 o;
    o[0] = (short)f2b(v.x * sc); o[1] = (short)f2b(v.y * sc);
    o[2] = (short)f2b(v.z * sc); o[3] = (short)f2b(v.w * sc);
    *(sv4*)(dst + i) = o;
  } else if (bid < 12288) {
    const int i = ((bid - 4096) * 256 + threadIdx.x) * 4;  // flat over 2*FFd*Ee
    const int r = i >> 10, c = i & 1023;
    const int rp = (r < FFd) ? ((r >> 4) * 32 + (r & 15))
                             : (((r - FFd) >> 4) * 32 + 16 + (r & 15));
    const float4 v = *(const float4*)(W1 + i);
    sv4 o;
    o[0] = (short)f2b(v.x); o[1] = (short)f2b(v.y);
    o[2] = (short)f2b(v.z); o[3] = (short)f2b(v.w);
    *(sv4*)(w116 + (size_t)rp * Ee + c) = o;
  } else {
    const int i = ((bid - 12288) * 256 + threadIdx.x) * 4;  // flat over Ee*FFd
    const float4 v = *(const float4*)(W2 + i);
    sv4 o;
    o[0] = (short)f2b(v.x); o[1] = (short)f2b(v.y);
    o[2] = (short)f2b(v.z); o[3] = (short)f2b(v.w);
    *(sv4*)(w216 + i) = o;
  }
}

// ---------------- V transpose: qkv V-slice [t][h*64+d] -> vT[b][h][d][t] ----------
__global__ __launch_bounds__(256) void vt_kernel(const unsigned short* __restrict__ qkv,
                                                 unsigned short* __restrict__ vT) {
  const int bh = blockIdx.y;               // b*16+h
  const int b = bh >> 4, h = bh & 15;
  const int tt = blockIdx.x * 64;          // token tile
  const int tid = threadIdx.x;
  __shared__ unsigned short tile[64][65];  // +1 pad
  const int tr = tid >> 2, tc4 = (tid & 3) * 16;
  const unsigned short* src = qkv + (size_t)(b * Tt + tt + tr) * (3 * Ee) + 2 * Ee + h * 64 + tc4;
  const sv8 a0 = *(const sv8*)src;
  const sv8 a1 = *(const sv8*)(src + 8);
#pragma unroll
  for (int j = 0; j < 8; ++j) { tile[tr][tc4 + j] = a0[j]; tile[tr][tc4 + 8 + j] = a1[j]; }
  __syncthreads();
  unsigned short* dst = vT + ((size_t)bh * 64 + tr) * Tt + tt + tc4;
  sv8 o0, o1;
#pragma unroll
  for (int j = 0; j < 8; ++j) { o0[j] = (short)tile[tc4 + j][tr]; o1[j] = (short)tile[tc4 + 8 + j][tr]; }
  *(sv8*)dst = o0;
  *(sv8*)(dst + 8) = o1;
}

// ---------------- LayerNorm (fp32 in, bf16 out), one block per row ----------------
__global__ __launch_bounds__(256) void ln_kernel(const float* __restrict__ x,
                                                 const float* __restrict__ g,
                                                 const float* __restrict__ b,
                                                 unsigned short* __restrict__ out) {
  const int row = blockIdx.x, tid = threadIdx.x;
  const float4 v = *(const float4*)(x + (size_t)row * Ee + tid * 4);
  float s = v.x + v.y + v.z + v.w;
  float ss = v.x * v.x + v.y * v.y + v.z * v.z + v.w * v.w;
#pragma unroll
  for (int off = 32; off; off >>= 1) { s += __shfl_down(s, off); ss += __shfl_down(ss, off); }
  __shared__ float red[16];
  const int w = tid >> 6, l = tid & 63;
  if (l == 0) { red[w] = s; red[8 + w] = ss; }
  __syncthreads();
  s = red[0] + red[1] + red[2] + red[3];
  ss = red[8] + red[9] + red[10] + red[11];
  const float mean = s * (1.f / Ee);
  const float rstd = rsqrtf(ss * (1.f / Ee) - mean * mean + EPSv);
  const float4 gv = *(const float4*)(g + tid * 4);
  const float4 bv = *(const float4*)(b + tid * 4);
  sv4 o;
  o[0] = (short)f2b((v.x - mean) * rstd * gv.x + bv.x);
  o[1] = (short)f2b((v.y - mean) * rstd * gv.y + bv.y);
  o[2] = (short)f2b((v.z - mean) * rstd * gv.z + bv.z);
  o[3] = (short)f2b((v.w - mean) * rstd * gv.w + bv.w);
  *(sv4*)(out + (size_t)row * Ee + tid * 4) = o;
}

// ---------------- bf16 GEMM (128xBN, 4 waves) — QKV / Wo / W2 ----------------
// Depth-2 pipeline (R11 structure). Chunk swizzle (T2).
template <int OUTF32, int HASBIAS, int BN, int GEGLU>
__global__ __launch_bounds__(256) void gemm_bt(const unsigned short* __restrict__ A,
                                               const unsigned short* __restrict__ Bw,
                                               void* __restrict__ Cout,
                                               const float* __restrict__ bias,
                                               const float* __restrict__ res,
                                               int M, int K) {
  constexpr int NI = BN / 32;  // per-wave n-frags (wave covers BN/2 cols)
  __shared__ unsigned short lA[3][128 * 32];
  __shared__ unsigned short lB[3][BN * 32];
  const int tid = threadIdx.x;
  const int l = tid & 63, w = tid >> 6;
  const int wr = w >> 1, wc = w & 1;
  const int rowbase = blockIdx.y * 128, colbase = blockIdx.x * BN;

  const fv4 zero4 = {0.f, 0.f, 0.f, 0.f};
  fv4 acc[4][NI];
#pragma unroll
  for (int i = 0; i < 4; ++i)
#pragma unroll
    for (int j = 0; j < NI; ++j) acc[i][j] = zero4;

  const int c0 = tid, c1 = tid + 256;
  const int sw0 = ((c0 & 3) ^ ((c0 >> 3) & 3)) * 8;
  const int sw1 = ((c1 & 3) ^ ((c1 >> 3) & 3)) * 8;
  const unsigned short* Ag0 = A + (size_t)(rowbase + (c0 >> 2)) * K + sw0;
  const unsigned short* Ag1 = A + (size_t)(rowbase + (c1 >> 2)) * K + sw1;
  const unsigned short* Bg0 = Bw + (size_t)(colbase + (c0 >> 2)) * K + sw0;
  const unsigned short* Bg1 = Bw + (size_t)(colbase + ((BN == 128 ? c1 : c0) >> 2)) * K +
                              (BN == 128 ? sw1 : sw0);

  const int nk = K >> 5;

  auto stage = [&](int buf) {
    load_lds16(Ag0, lA[buf] + c0 * 8);
    load_lds16(Ag1, lA[buf] + c1 * 8);
    load_lds16(Bg0, lB[buf] + c0 * 8);
    if (BN == 128) load_lds16(Bg1, lB[buf] + c1 * 8);
    Ag0 += 32; Ag1 += 32; Bg0 += 32; Bg1 += 32;
  };

  stage(0);
  stage(1);
  if constexpr (BN == 128) WAIT_VM(4); else WAIT_VM(3);
  __builtin_amdgcn_s_barrier();

  int cur = 0;
  for (int t = 0; t < nk; ++t) {
    const int pf = (cur + 2 >= 3) ? cur - 1 : cur + 2;  // (cur+2)%3
    if (t + 2 < nk) stage(pf);
    sv8 af[4], bfr[NI];
#pragma unroll
    for (int i = 0; i < 4; ++i) {
      const int ra = wr * 64 + i * 16 + (l & 15);
      af[i] = *(const sv8*)(lA[cur] + ra * 32 + (((l >> 4) ^ ((ra >> 1) & 3)) * 8));
    }
#pragma unroll
    for (int i = 0; i < NI; ++i) {
      const int rb = wc * (BN / 2) + i * 16 + (l & 15);
      bfr[i] = *(const sv8*)(lB[cur] + rb * 32 + (((l >> 4) ^ ((rb >> 1) & 3)) * 8));
    }
    __builtin_amdgcn_s_setprio(1);
#pragma unroll
    for (int mi = 0; mi < 4; ++mi)
#pragma unroll
      for (int ni = 0; ni < NI; ++ni)
        acc[mi][ni] = __builtin_amdgcn_mfma_f32_16x16x32_bf16(af[mi], bfr[ni], acc[mi][ni], 0, 0, 0);
    __builtin_amdgcn_s_setprio(0);
    if (t + 2 < nk) {
      if constexpr (BN == 128) WAIT_VM(4); else WAIT_VM(3);
      __builtin_amdgcn_s_barrier();
    } else if (t + 1 < nk) {
      WAIT_VM(0);
      __builtin_amdgcn_s_barrier();
    }
    cur = (cur + 1 >= 3) ? 0 : cur + 1;
  }

  const int r0 = rowbase + wr * 64 + ((l >> 4) * 4);
  const int ccol = colbase + wc * (BN / 2) + (l & 15);
#pragma unroll
  for (int mi = 0; mi < 4; ++mi) {
#pragma unroll
    for (int j = 0; j < 4; ++j) {
      const size_t r = (size_t)(r0 + mi * 16 + j);
      if (GEGLU) {
#pragma unroll
        for (int p = 0; p < NI / 2; ++p) {
          const int ca = ccol + p * 32;
          const int ocol = ((ca >> 5) << 4) | (ca & 15);
          const float av = acc[mi][2 * p][j] + bias[ocol];
          const float gv = acc[mi][2 * p + 1][j] + bias[ocol + (M >> 1)];
          const float y = 0.7978845608028654f * (gv + 0.044715f * gv * gv * gv);
          const float e = exp2f(2.8853900817779268f * y);
          const float gel = gv * (1.f - 1.f / (e + 1.f));
          ((unsigned short*)Cout)[r * (size_t)(M >> 1) + ocol] = f2b(av * gel);
        }
      } else {
#pragma unroll
        for (int ni = 0; ni < NI; ++ni) {
          const int c = ccol + ni * 16;
          float vv = acc[mi][ni][j];
          if (HASBIAS) vv += bias[c];
          if (OUTF32) {
            ((float*)Cout)[r * M + c] = res[r * M + c] + vv;
          } else {
            ((unsigned short*)Cout)[r * M + c] = f2b(vv);
          }
        }
      }
    }
  }
}

// ------- 256x256 phase-interleaved bf16 GEMM (R12 variant — best measured W1) ------
// 512 threads = 8 waves (2 Mrow x 4 Ncol); per-wave output 128x64; BK=64 split into
// 2 K-halves per operand. LDS = 128 KB. Staging quantum = one 16KB half, fixed order
// A0,B0,A1,B1. Counted waits at ph0/ph2 only (vmcnt(4)): 2 halves always in flight
// across barriers; never drained mid-loop; tail tile uses vmcnt(0) at ph2.
template <int GEGLU>
__global__ __launch_bounds__(512, 2) void gemm256(const unsigned short* __restrict__ A,
                                                  const unsigned short* __restrict__ Bw,
                                                  void* __restrict__ Cout,
                                                  const float* __restrict__ bias,
                                                  int M, int K) {
  __shared__ unsigned short Ah[2][2][256 * 32];  // [dbuf][khalf]
  __shared__ unsigned short Bh[2][2][256 * 32];
  const int tid = threadIdx.x;
  const int l = tid & 63, w = tid >> 6;
  const int wrow = w >> 2, wcol = w & 3;   // 2 x 4 wave grid
  const int nbase = blockIdx.y * 256, mbase = blockIdx.x * 256;

  const fv4 zero4 = {0.f, 0.f, 0.f, 0.f};
  fv4 acc[8][4];
#pragma unroll
  for (int i = 0; i < 8; ++i)
#pragma unroll
    for (int j = 0; j < 4; ++j) acc[i][j] = zero4;

  // staging: each half = 1024 slots of 16B; thread handles slots tid and tid+512.
  const int s0 = tid, s1 = tid + 512;
  const int r0 = s0 >> 2, x0 = (((s0 & 3) ^ ((r0 >> 1) & 3))) * 8;
  const int r1 = s1 >> 2, x1 = (((s1 & 3) ^ ((r1 >> 1) & 3))) * 8;
  const unsigned short* As0 = A + (size_t)(nbase + r0) * K + x0;
  const unsigned short* As1 = A + (size_t)(nbase + r1) * K + x1;
  const unsigned short* Bs0 = Bw + (size_t)(mbase + r0) * K + x0;
  const unsigned short* Bs1 = Bw + (size_t)(mbase + r1) * K + x1;

  const int nk = K >> 6;

  auto stA = [&](int db, int kh, int kof) {
    load_lds16(As0 + kof + kh * 32, &Ah[db][kh][s0 * 8]);
    load_lds16(As1 + kof + kh * 32, &Ah[db][kh][s1 * 8]);
  };
  auto stB = [&](int db, int kh, int kof) {
    load_lds16(Bs0 + kof + kh * 32, &Bh[db][kh][s0 * 8]);
    load_lds16(Bs1 + kof + kh * 32, &Bh[db][kh][s1 * 8]);
  };

  // ds_read bases (elems): per-lane chunk position is LANE-CONSTANT:
  // chunk' = (l>>4) ^ ((r>>1)&3), and (r>>1)&3 == (l>>1)&3 since frag row = 16m+(l&15).
  const int cl = (((l >> 4) ^ ((l >> 1) & 3))) * 8;
  const int arl = (wrow * 128 + (l & 15)) * 32 + cl;
  const int brl = (wcol * 64 + (l & 15)) * 32 + cl;

  // prologue: tile 0's four halves, in the canonical order A0,B0,A1,B1
  stA(0, 0, 0); stB(0, 0, 0); stA(0, 1, 0); stB(0, 1, 0);

  for (int t = 0; t < nk; ++t) {
    const int st = t & 1, sf = st ^ 1;
    const int kof = (t + 1) * 64;
    const bool pre = (t + 1 < nk);
    sv8 af[8], b0, b1;

    // ---- ph0: gate on A0,B0 of tile t; stage A0(t+1); MFMA ks0 x ni0-1 ----
    WAIT_VM(4);
    __builtin_amdgcn_s_barrier();
    __builtin_amdgcn_sched_barrier(0);
    if (pre) stA(sf, 0, kof);
#pragma unroll
    for (int mi = 0; mi < 8; ++mi) af[mi] = *(const sv8*)(&Ah[st][0][arl + mi * 512]);
    b0 = *(const sv8*)(&Bh[st][0][brl]);
    b1 = *(const sv8*)(&Bh[st][0][brl + 512]);
    __builtin_amdgcn_s_setprio(1);
#pragma unroll
    for (int mi = 0; mi < 8; ++mi) {
      acc[mi][0] = __builtin_amdgcn_mfma_f32_16x16x32_bf16(af[mi], b0, acc[mi][0], 0, 0, 0);
      acc[mi][1] = __builtin_amdgcn_mfma_f32_16x16x32_bf16(af[mi], b1, acc[mi][1], 0, 0, 0);
    }
    __builtin_amdgcn_s_setprio(0);

    // ---- ph1: stage B0(t+1); MFMA ks0 x ni2-3 (af reused) ----
    if (pre) stB(sf, 0, kof);
    b0 = *(const sv8*)(&Bh[st][0][brl + 2 * 512]);
    b1 = *(const sv8*)(&Bh[st][0][brl + 3 * 512]);
    __builtin_amdgcn_s_setprio(1);
#pragma unroll
    for (int mi = 0; mi < 8; ++mi) {
      acc[mi][2] = __builtin_amdgcn_mfma_f32_16x16x32_bf16(af[mi], b0, acc[mi][2], 0, 0, 0);
      acc[mi][3] = __builtin_amdgcn_mfma_f32_16x16x32_bf16(af[mi], b1, acc[mi][3], 0, 0, 0);
    }
    __builtin_amdgcn_s_setprio(0);

    // ---- ph2: gate on A1,B1 of tile t; stage A1(t+1); MFMA ks1 x ni0-1 ----
    if (pre) { WAIT_VM(4); } else { WAIT_VM(0); }
    __builtin_amdgcn_s_barrier();
    __builtin_amdgcn_sched_barrier(0);
    if (pre) stA(sf, 1, kof);
#pragma unroll
    for (int mi = 0; mi < 8; ++mi) af[mi] = *(const sv8*)(&Ah[st][1][arl + mi * 512]);
    b0 = *(const sv8*)(&Bh[st][1][brl]);
    b1 = *(const sv8*)(&Bh[st][1][brl + 512]);
    __builtin_amdgcn_s_setprio(1);
#pragma unroll
    for (int mi = 0; mi < 8; ++mi) {
      acc[mi][0] = __builtin_amdgcn_mfma_f32_16x16x32_bf16(af[mi], b0, acc[mi][0], 0, 0, 0);
      acc[mi][1] = __builtin_amdgcn_mfma_f32_16x16x32_bf16(af[mi], b1, acc[mi][1], 0, 0, 0);
    }
    __builtin_amdgcn_s_setprio(0);

    // ---- ph3: stage B1(t+1); MFMA ks1 x ni2-3 ----
    if (pre) stB(sf, 1, kof);
    b0 = *(const sv8*)(&Bh[st][1][brl + 2 * 512]);
    b1 = *(const sv8*)(&Bh[st][1][brl + 3 * 512]);
    __builtin_amdgcn_s_setprio(1);
#pragma unroll
    for (int mi = 0; mi < 8; ++mi) {
      acc[mi][2] = __builtin_amdgcn_mfma_f32_16x16x32_bf16(af[mi], b0, acc[mi][2], 0, 0, 0);
      acc[mi][3] = __builtin_amdgcn_mfma_f32_16x16x32_bf16(af[mi], b1, acc[mi][3], 0, 0, 0);
    }
    __builtin_amdgcn_s_setprio(0);
  }

  // ---- epilogue: C/D layout col=lane&15, row=(l>>4)*4+j ----
  const int rbase = nbase + wrow * 128 + ((l >> 4) * 4);
  const int cbase = mbase + wcol * 64 + (l & 15);
#pragma unroll
  for (int mi = 0; mi < 8; ++mi) {
#pragma unroll
    for (int j = 0; j < 4; ++j) {
      const size_t r = (size_t)(rbase + mi * 16 + j);
      if (GEGLU) {
#pragma unroll
        for (int p = 0; p < 2; ++p) {
          const int ca = cbase + p * 32;                   // even fragment (a); bit4 == 0
          const int ocol = ((ca >> 5) << 4) | (ca & 15);   // original column
          const float av = acc[mi][2 * p][j] + bias[ocol];
          const float gv = acc[mi][2 * p + 1][j] + bias[ocol + (M >> 1)];
          const float y = 0.7978845608028654f * (gv + 0.044715f * gv * gv * gv);
          const float e = exp2f(2.8853900817779268f * y);  // exp(2y)
          const float gel = gv * (1.f - 1.f / (e + 1.f));  // == 0.5*g*(1+tanh(y))
          ((unsigned short*)Cout)[r * (size_t)(M >> 1) + ocol] = f2b(av * gel);
        }
      } else {
#pragma unroll
        for (int ni = 0; ni < 4; ++ni) {
          const int c = cbase + ni * 16;
          ((unsigned short*)Cout)[r * (size_t)M + c] = f2b(acc[mi][ni][j]);
        }
      }
    }
  }
}

// ---------------- flash attention (unchanged) ----------------
__global__ __launch_bounds__(256) void attn_kernel(const unsigned short* __restrict__ Q,
                                                   const unsigned short* __restrict__ Kb,
                                                   const unsigned short* __restrict__ vT,
                                                   unsigned short* __restrict__ O,
                                                   int ld) {
  const int bidl = ((blockIdx.x & 7) << 7) + (blockIdx.x >> 3);  // 1024 = 8 XCD x 128
  const int bh = bidl >> 5;
  const int b = bh / Hh, h = bh % Hh;
  const int q0 = (bidl & 31) * 64;
  const int tid = threadIdx.x, l = tid & 63, w = tid >> 6;
  const size_t base = (size_t)b * Tt * ld + (size_t)h * Dd;
  const size_t baseO = (size_t)b * Tt * Ee + (size_t)h * Dd;
  const unsigned short* vTb = vT + (size_t)bh * 64 * Tt;  // [64 d][2048 t]

  __shared__ unsigned short Kt[2][64 * 64];
  __shared__ unsigned short Vt[2][64 * 64];
  __shared__ unsigned short Pt[4][16 * 64];

  sv8 qf0, qf1;
  {
    const unsigned short* qp = Q + base + (size_t)(q0 + w * 16 + (l & 15)) * ld + (l >> 4) * 8;
    qf0 = *(const sv8*)qp;
    qf1 = *(const sv8*)(qp + 32);
  }

  const fv4 zero4 = {0.f, 0.f, 0.f, 0.f};
  fv4 acc_o[4];
#pragma unroll
  for (int i = 0; i < 4; ++i) acc_o[i] = zero4;
  float Mx = -INFINITY;
  float Lp[4];
#pragma unroll
  for (int j = 0; j < 4; ++j) Lp[j] = 0.f;

  const int c0 = tid, c1 = tid + 256;
  const int r0c = c0 >> 3, xc0 = c0 & 7;
  const int r1c = c1 >> 3, xc1 = c1 & 7;

  load_lds16(Kb + base + (size_t)(r0c)*ld + (xc0 ^ (r0c & 7)) * 8, Kt[0] + c0 * 8);
  load_lds16(Kb + base + (size_t)(r1c)*ld + (xc1 ^ (r1c & 7)) * 8, Kt[0] + c1 * 8);
  load_lds16(vTb + (size_t)(r0c)*Tt + (xc0 ^ (r0c & 7)) * 8, Vt[0] + c0 * 8);
  load_lds16(vTb + (size_t)(r1c)*Tt + (xc1 ^ (r1c & 7)) * 8, Vt[0] + c1 * 8);
  __syncthreads();

  int cur = 0;
  for (int kt = 0; kt < Tt / 64; ++kt) {
    const int nx = cur ^ 1;
    if (kt + 1 < Tt / 64) {
      load_lds16(Kb + base + (size_t)((kt + 1) * 64 + r0c) * ld + (xc0 ^ (r0c & 7)) * 8, Kt[nx] + c0 * 8);
      load_lds16(Kb + base + (size_t)((kt + 1) * 64 + r1c) * ld + (xc1 ^ (r1c & 7)) * 8, Kt[nx] + c1 * 8);
      load_lds16(vTb + (size_t)(r0c)*Tt + (kt + 1) * 64 + (xc0 ^ (r0c & 7)) * 8, Vt[nx] + c0 * 8);
      load_lds16(vTb + (size_t)(r1c)*Tt + (kt + 1) * 64 + (xc1 ^ (r1c & 7)) * 8, Vt[nx] + c1 * 8);
    }

    fv4 s[4];
    __builtin_amdgcn_s_setprio(1);
#pragma unroll
    for (int ks = 0; ks < 4; ++ks) {
      const int row = ks * 16 + (l & 15);
      const sv8 kf0 = *(const sv8*)(Kt[cur] + row * 64 + (((l >> 4) ^ (row & 7)) * 8));
      const sv8 kf1 = *(const sv8*)(Kt[cur] + row * 64 + (((4 + (l >> 4)) ^ (row & 7)) * 8));
      fv4 t = zero4;
      t = __builtin_amdgcn_mfma_f32_16x16x32_bf16(qf0, kf0, t, 0, 0, 0);
      t = __builtin_amdgcn_mfma_f32_16x16x32_bf16(qf1, kf1, t, 0, 0, 0);
      s[ks] = t;
    }
    __builtin_amdgcn_s_setprio(0);

    float m01 = fmaxf(fmaxf(s[0][0], s[0][1]), fmaxf(s[0][2], s[0][3]));
    float m1 = fmaxf(fmaxf(s[1][0], s[1][1]), fmaxf(s[1][2], s[1][3]));
    float m2 = fmaxf(fmaxf(s[2][0], s[2][1]), fmaxf(s[2][2], s[2][3]));
    float m3 = fmaxf(fmaxf(s[3][0], s[3][1]), fmaxf(s[3][2], s[3][3]));
    float tm = fmaxf(fmaxf(m01, m1), fmaxf(m2, m3));
    if (__any(tm > Mx + 11.5f)) {
      float mt = tm;
#pragma unroll
      for (int off = 1; off < 16; off <<= 1) mt = fmaxf(mt, __shfl_xor(mt, off, 16));
      const float mnew = fmaxf(Mx, mt);
      const float alpha = exp2f(Mx - mnew);
      Mx = mnew;
#pragma unroll
      for (int j = 0; j < 4; ++j) {
        Lp[j] *= alpha;
#pragma unroll
        for (int dsb = 0; dsb < 4; ++dsb) acc_o[dsb][j] *= alpha;
      }
    }
#pragma unroll
    for (int ks = 0; ks < 4; ++ks)
#pragma unroll
      for (int j = 0; j < 4; ++j) {
        const float p = exp2f(s[ks][j] - Mx);
        s[ks][j] = p;
        Lp[j] += p;
      }
#pragma unroll
    for (int ks = 0; ks < 4; ++ks)
#pragma unroll
      for (int j = 0; j < 4; ++j) {
        const int q = (l >> 4) * 4 + j, k = ks * 16 + (l & 15);
        Pt[w][q * 64 + ((((k >> 3) ^ (q & 7)) & 7) * 8) + (k & 7)] = f2b_rtz(s[ks][j]);
      }
    LGKM0;

    __builtin_amdgcn_s_setprio(1);
#pragma unroll
    for (int kcn = 0; kcn < 2; ++kcn) {
      const int qr = l & 15;
      const sv8 pf = *(const sv8*)(&Pt[w][qr * 64 + (((kcn * 4 + (l >> 4)) ^ (qr & 7)) * 8)]);
#pragma unroll
      for (int dsb = 0; dsb < 4; ++dsb) {
        const int row = dsb * 16 + (l & 15);
        const int chunk = kcn * 4 + (l >> 4);
        const sv8 vf = *(const sv8*)(Vt[cur] + row * 64 + ((chunk ^ (row & 7)) * 8));
        acc_o[dsb] = __builtin_amdgcn_mfma_f32_16x16x32_bf16(pf, vf, acc_o[dsb], 0, 0, 0);
      }
    }
    __builtin_amdgcn_s_setprio(0);

    __syncthreads();
    cur = nx;
  }

#pragma unroll
  for (int j = 0; j < 4; ++j) {
    float t = Lp[j];
#pragma unroll
    for (int off = 1; off < 16; off <<= 1) t += __shfl_xor(t, off, 16);
    const float inv = 1.f / t;
    unsigned short* op = O + baseO + (size_t)(q0 + w * 16 + (l >> 4) * 4 + j) * Ee;
#pragma unroll
    for (int dsb = 0; dsb < 4; ++dsb)
      op[dsb * 16 + (l & 15)] = f2b(acc_o[dsb][j] * inv);
  }
}

extern "C" void kernel_launch(void* const* d_in, const int* in_sizes, int n_in,
                              void* d_out, int out_size, void* d_ws, size_t ws_size,
                              hipStream_t stream) {
  (void)in_sizes; (void)n_in; (void)out_size; (void)ws_size;
  const float* src  = (const float*)d_in[0];
  const float* Wq   = (const float*)d_in[1];
  const float* Wk   = (const float*)d_in[2];
  const float* Wv   = (const float*)d_in[3];
  const float* Wo   = (const float*)d_in[4];
  const float* W1   = (const float*)d_in[5];
  const float* b1   = (const float*)d_in[6];
  const float* W2   = (const float*)d_in[7];
  const float* b2   = (const float*)d_in[8];
  const float* ln1w = (const float*)d_in[9];
  const float* ln1b = (const float*)d_in[10];
  const float* ln2w = (const float*)d_in[11];
  const float* ln2b = (const float*)d_in[12];
  float* out = (float*)d_out;

  char* ws = (char*)d_ws;
  size_t off = 0;
  auto alloc = [&](size_t bytes) { char* p = ws + off; off += bytes; return p; };
  unsigned short* wqkv = (unsigned short*)alloc((size_t)3 * Ee * Ee * 2);  // Wq|Wk|Wv rows
  unsigned short* wo16 = (unsigned short*)alloc((size_t)Ee * Ee * 2);
  unsigned short* w116 = (unsigned short*)alloc((size_t)2 * FFd * Ee * 2); // interleaved
  unsigned short* w216 = (unsigned short*)alloc((size_t)Ee * FFd * 2);
  unsigned short* h16  = (unsigned short*)alloc((size_t)NN * Ee * 2);
  unsigned short* qkv  = (unsigned short*)alloc((size_t)NN * 3 * Ee * 2);  // [row][3E]
  unsigned short* a16  = (unsigned short*)alloc((size_t)NN * Ee * 2);
  float* xbuf          = (float*)alloc((size_t)NN * Ee * 4);
  unsigned short* vT   = (unsigned short*)alloc((size_t)NN * Ee * 2);      // [b][h][64][T]
  unsigned short* f16  = qkv;  // reuse qkv+a16 region (32 MB) after attention done

  const float s2 = 0.125f * 1.4426950408889634f;  // 1/sqrt(D) * log2(e), folded into Wq

  dim3 blk(256);
  // all 6 weight converts in one launch
  cvt_all_kernel<<<dim3(16384), blk, 0, stream>>>(Wq, Wk, Wv, Wo, W1, W2,
                                                  wqkv, wo16, w116, w216, s2);

  ln_kernel<<<dim3(NN), blk, 0, stream>>>(src, ln1w, ln1b, h16);

  // fused QKV projection: [4096,1024] x [3072,1024]^T -> [4096,3072]
  gemm_bt<0, 0, 128, 0><<<dim3(3 * Ee / 128, NN / 128), blk, 0, stream>>>(h16, wqkv, qkv, nullptr, nullptr, 3 * Ee, Ee);

  // V transpose: [t][h*64+d] -> vT[b][h][d][t]
  vt_kernel<<<dim3(Tt / 64, Bb * Hh), blk, 0, stream>>>(qkv, vT);

  attn_kernel<<<dim3(1024), blk, 0, stream>>>(qkv, qkv + Ee, vT, a16, 3 * Ee);

  // Wo projection + residual (BN=64: 512 blocks, 2/CU)
  gemm_bt<1, 0, 64, 0><<<dim3(Ee / 64, NN / 128), blk, 0, stream>>>(a16, wo16, xbuf, nullptr, src, Ee, Ee);

  ln_kernel<<<dim3(NN), blk, 0, stream>>>(xbuf, ln2w, ln2b, h16);

  // W1 (block-16 interleaved) + lane-local GEGLU, 256x256 phase-interleaved kernel
  gemm256<1><<<dim3(2 * FFd / 256, NN / 256), dim3(512), 0, stream>>>(h16, w116, f16, b1, 2 * FFd, Ee);

  // W2 projection + bias + residual (BN=64: 512 blocks, 2/CU)
  gemm_bt<1, 1, 64, 0><<<dim3(Ee / 64, NN / 128), blk, 0, stream>>>(f16, w216, out, b2, xbuf, Ee, FFd);
}